// Round 15
// baseline (58.188 us; speedup 1.0000x reference)
//
#include <hip/hip_runtime.h>

#define DIM 81
#define RA  63
#define RB  32
#define ZT  32
#define XS  104   // X LDS row stride (f16)
#define OS  100   // out-staging row stride (f32)

// workspace offsets (bytes)
#define OFF_SHAA 0        // [at2][kk6][lane64][j8] f16 : 12288 B  (GEMM1 A: sha, i PARITY-PERMUTED k)
#define OFF_SHAT 12288    // [it3][ks4][lane64][j8] f16 : 12288 B  (GEMM2 B: sha transposed, i natural)
#define OFF_SHBH 24576    // [b32][kk6][hi2][j8]   f16 :  6144 B  (shb frag-broadcast, PARITY-PERMUTED k)
#define OFF_SHBQ 30720    // [b32][it3][l32]       f32 : 12288 B  (shb[b,i]*qw[b], i natural)
#define OFF_PERM 43008    // int[96]: src i for each permuted k (-1 = pad)
#define WS_NEED  43392

// LDS: [0,6144) shbH | [6144,18432) shbq | [18432,+25600) xp/ob union
#define LDS_TBL   18432
#define LDS_BYTES (18432 + 25600)

typedef _Float16 half8 __attribute__((ext_vector_type(8)));
typedef __fp16  fp16x2 __attribute__((ext_vector_type(2)));
typedef float floatx16 __attribute__((ext_vector_type(16)));

union H8U { unsigned u[4]; half8 h; };
union H2U { fp16x2 h; unsigned u; };

// parity-permuted k axis: positions 0..47 = even (l+|m|) parity i's (45 valid),
// 48..95 = odd parity (36 valid). Returns source i or -1 (zero pad).
__device__ int src_of_k(int k) {
    const int want = (k < 48) ? 0 : 1;
    const int rank = (k < 48) ? k : k - 48;
    int cnt = 0;
    for (int i = 0; i < DIM; ++i) {
        int l = 0;
        while ((l + 1) * (l + 1) <= i) ++l;
        int m = i - l * l - l;
        int p = (l + (m < 0 ? -m : m)) & 1;
        if (p == want) { if (cnt == rank) return i; ++cnt; }
    }
    return -1;
}

// ---------------- precompute packed tables (43 KB + perm) ----------------
__global__ __launch_bounds__(256) void precompute_fact(
    const float* __restrict__ shb, const float* __restrict__ sha,
    const float* __restrict__ qw, char* __restrict__ wsp)
{
    _Float16* shaAP = (_Float16*)(wsp + OFF_SHAA);
    _Float16* shaTP = (_Float16*)(wsp + OFF_SHAT);
    _Float16* shbHP = (_Float16*)(wsp + OFF_SHBH);
    float*    shbqP = (float*)(wsp + OFF_SHBQ);
    int*      permP = (int*)(wsp + OFF_PERM);

    int idx = blockIdx.x * 256 + threadIdx.x;
    if (idx < 6144) {                       // shaAP: rows a, k permuted-i
        int j = idx & 7, lane = (idx >> 3) & 63, g = idx >> 9;   // g = at*6+kk
        int at = g / 6, kk = g - at * 6;
        int a = at * 32 + (lane & 31);
        int k = kk * 16 + (lane >> 5) * 8 + j;
        int si = src_of_k(k);
        float v = (a < RA && si >= 0) ? sha[a * DIM + si] : 0.f;
        shaAP[idx] = (_Float16)v;
    } else if (idx < 12288) {               // shaTP: cols i (natural), k = a
        int t = idx - 6144;
        int j = t & 7, lane = (t >> 3) & 63, g = t >> 9;          // g = it*4+ks
        int it = g >> 2, ks = g & 3;
        int a = ks * 16 + (lane >> 5) * 8 + j;
        int i = it * 32 + (lane & 31);
        float v = (a < RA && i < DIM) ? sha[a * DIM + i] : 0.f;
        shaTP[t] = (_Float16)v;
    } else if (idx < 15360) {               // shbHP: per-(b,kk,hi) broadcast, k permuted-i
        int t = idx - 12288;
        int j = t & 7, hi = (t >> 3) & 1, g = t >> 4;             // g = b*6+kk
        int b = g / 6, kk = g - b * 6;
        int k = kk * 16 + hi * 8 + j;
        int si = src_of_k(k);
        float v = (si >= 0) ? shb[b * DIM + si] : 0.f;
        shbHP[t] = (_Float16)v;
    } else if (idx < 18432) {               // shbqP: f32 scale per (b, i natural)
        int t = idx - 15360;
        int l = t & 31, g = t >> 5;                               // g = b*3+it
        int b = g / 3, it = g - b * 3;
        int i = it * 32 + l;
        float v = (i < DIM) ? shb[b * DIM + i] * qw[b] : 0.f;
        shbqP[t] = v;
    } else if (idx < 18528) {               // perm table
        permP[idx - 18432] = src_of_k(idx - 18432);
    }
}

// GEMM1 pair step for one at: E/O partial sums -> P f16 frags for b (E+O) and 31-b (E-O)
#define G1_PAIR(AT, FB, FP) do {                                                            \
    floatx16 e0, e1, o0, o1;                                                                \
    _Pragma("unroll") for (int r = 0; r < 16; ++r) { e0[r]=0.f; e1[r]=0.f; o0[r]=0.f; o1[r]=0.f; } \
    _Pragma("unroll") for (int kk = 0; kk < 3; ++kk) {                                      \
        const half8 sf = *(const half8*)(shbH_l + ((b * 6 + kk) * 2 + hi) * 8);             \
        const half8 aA = *(const half8*)(shaAP + (((AT) * 6 + kk) * 64 + l) * 8);           \
        const half8 aS = aA * sf;                                                           \
        e0 = __builtin_amdgcn_mfma_f32_32x32x16_f16(aS, xfr[0][kk], e0, 0, 0, 0);           \
        e1 = __builtin_amdgcn_mfma_f32_32x32x16_f16(aS, xfr[1][kk], e1, 0, 0, 0);           \
    }                                                                                       \
    _Pragma("unroll") for (int kk = 3; kk < 6; ++kk) {                                      \
        const half8 sf = *(const half8*)(shbH_l + ((b * 6 + kk) * 2 + hi) * 8);             \
        const half8 aA = *(const half8*)(shaAP + (((AT) * 6 + kk) * 64 + l) * 8);           \
        const half8 aS = aA * sf;                                                           \
        o0 = __builtin_amdgcn_mfma_f32_32x32x16_f16(aS, xfr[0][kk], o0, 0, 0, 0);           \
        o1 = __builtin_amdgcn_mfma_f32_32x32x16_f16(aS, xfr[1][kk], o1, 0, 0, 0);           \
    }                                                                                       \
    unsigned qb[8], qm[8];                                                                  \
    _Pragma("unroll") for (int j = 0; j < 8; ++j) {                                         \
        H2U tb, tm;                                                                         \
        float pb0 = (e0[2*j]   + o0[2*j])   * (e1[2*j]   + o1[2*j]);                        \
        float pb1 = (e0[2*j+1] + o0[2*j+1]) * (e1[2*j+1] + o1[2*j+1]);                      \
        tb.h = __builtin_amdgcn_cvt_pkrtz(pb0, pb1);                                        \
        float pm0 = (e0[2*j]   - o0[2*j])   * (e1[2*j]   - o1[2*j]);                        \
        float pm1 = (e0[2*j+1] - o0[2*j+1]) * (e1[2*j+1] - o1[2*j+1]);                      \
        tm.h = __builtin_amdgcn_cvt_pkrtz(pm0, pm1);                                        \
        qb[j] = tb.u; qm[j] = tm.u;                                                         \
    }                                                                                       \
    asm volatile("v_permlane32_swap_b32 %0, %1" : "+v"(qb[0]), "+v"(qb[2]));                \
    asm volatile("v_permlane32_swap_b32 %0, %1" : "+v"(qb[1]), "+v"(qb[3]));                \
    asm volatile("v_permlane32_swap_b32 %0, %1" : "+v"(qb[4]), "+v"(qb[6]));                \
    asm volatile("v_permlane32_swap_b32 %0, %1" : "+v"(qb[5]), "+v"(qb[7]));                \
    asm volatile("v_permlane32_swap_b32 %0, %1" : "+v"(qm[0]), "+v"(qm[2]));                \
    asm volatile("v_permlane32_swap_b32 %0, %1" : "+v"(qm[1]), "+v"(qm[3]));                \
    asm volatile("v_permlane32_swap_b32 %0, %1" : "+v"(qm[4]), "+v"(qm[6]));                \
    asm volatile("v_permlane32_swap_b32 %0, %1" : "+v"(qm[5]), "+v"(qm[7]));                \
    _Pragma("unroll") for (int w = 0; w < 8; ++w) { FB[w] = qb[w]; FP[w] = qm[w]; }         \
} while (0)

// ---------------- main kernel: parity-paired b, halved GEMM1 ----------------
__global__ __launch_bounds__(256, 1) void gaunt_fact(
    const float* __restrict__ x1, const float* __restrict__ x2,
    const char* __restrict__ wsp, float* __restrict__ out)
{
    const _Float16* shaAP = (const _Float16*)(wsp + OFF_SHAA);
    const _Float16* shaTP = (const _Float16*)(wsp + OFF_SHAT);
    const int*      permG = (const int*)(wsp + OFF_PERM);

    __shared__ __align__(16) char lds[LDS_BYTES];
    const _Float16* shbH_l = (const _Float16*)lds;
    const float*    shbq_l = (const float*)(lds + 6144);
    _Float16* xp = (_Float16*)(lds + LDS_TBL);   // [2][ZT][XS]
    float*    ob = (float*)(lds + LDS_TBL);      // [2][ZT][OS]

    const int tid = threadIdx.x;
    const int z0  = blockIdx.x * ZT;

    // stage hot tables global->LDS
    for (int i = tid; i < LDS_TBL / 16; i += 256)
        ((uint4*)lds)[i] = ((const uint4*)(wsp + OFF_SHBH))[i];

    // stage X1,X2 -> f16 LDS with parity permutation of columns
    for (int idx = tid; idx < 2 * ZT * 96; idx += 256) {
        int in = idx / (ZT * 96), t = idx - in * (ZT * 96);
        int r = t / 96, c = t - r * 96;
        int si = permG[c];
        const float* src = in ? x2 : x1;
        float v = (si >= 0) ? src[(size_t)(z0 + r) * DIM + si] : 0.f;
        xp[in * (ZT * XS) + r * XS + c] = (_Float16)v;
    }
    __syncthreads();

    const int l = tid & 63, l31 = l & 31, hi = l >> 5;
    const int nw = tid >> 6;   // wave 0..3, owns b = nw*4 .. +4 (pairs with 31-b)

    // X B-frags resident in VGPR (48 regs), permuted k order
    half8 xfr[2][6];
    #pragma unroll
    for (int in = 0; in < 2; ++in)
        #pragma unroll
        for (int kk = 0; kk < 6; ++kk)
            xfr[in][kk] = *(const half8*)(xp + in * (ZT * XS) + l31 * XS + kk * 16 + hi * 8);
    __syncthreads();   // xp reads done; ob (aliased) writable later

    floatx16 accO[3];
    #pragma unroll
    for (int it = 0; it < 3; ++it)
        #pragma unroll
        for (int r = 0; r < 16; ++r) accO[it][r] = 0.f;

    // GEMM2 + scaled accumulate (i natural order); bT streamed from L1
    auto gemm2_acc = [&](int bb, const unsigned* fa0, const unsigned* fa1) {
        const float s0 = shbq_l[(bb * 3 + 0) * 32 + l31];
        const float s1 = shbq_l[(bb * 3 + 1) * 32 + l31];
        const float s2 = shbq_l[(bb * 3 + 2) * 32 + l31];
        #pragma unroll
        for (int it = 0; it < 3; ++it) {
            floatx16 R;
            #pragma unroll
            for (int r = 0; r < 16; ++r) R[r] = 0.f;
            {
                const half8 bT0 = *(const half8*)(shaTP + ((it * 4 + 0) * 64 + l) * 8);
                const half8 bT1 = *(const half8*)(shaTP + ((it * 4 + 1) * 64 + l) * 8);
                H8U a0, a1;
                a0.u[0] = fa0[0]; a0.u[1] = fa0[1]; a0.u[2] = fa0[2]; a0.u[3] = fa0[3];
                a1.u[0] = fa0[4]; a1.u[1] = fa0[5]; a1.u[2] = fa0[6]; a1.u[3] = fa0[7];
                R = __builtin_amdgcn_mfma_f32_32x32x16_f16(a0.h, bT0, R, 0, 0, 0);
                R = __builtin_amdgcn_mfma_f32_32x32x16_f16(a1.h, bT1, R, 0, 0, 0);
            }
            {
                const half8 bT0 = *(const half8*)(shaTP + ((it * 4 + 2) * 64 + l) * 8);
                const half8 bT1 = *(const half8*)(shaTP + ((it * 4 + 3) * 64 + l) * 8);
                H8U a0, a1;
                a0.u[0] = fa1[0]; a0.u[1] = fa1[1]; a0.u[2] = fa1[2]; a0.u[3] = fa1[3];
                a1.u[0] = fa1[4]; a1.u[1] = fa1[5]; a1.u[2] = fa1[6]; a1.u[3] = fa1[7];
                R = __builtin_amdgcn_mfma_f32_32x32x16_f16(a0.h, bT0, R, 0, 0, 0);
                R = __builtin_amdgcn_mfma_f32_32x32x16_f16(a1.h, bT1, R, 0, 0, 0);
            }
            const float s = (it == 0) ? s0 : (it == 1) ? s1 : s2;
            accO[it] += R * s;
        }
    };

    #pragma unroll 1
    for (int pi = 0; pi < 4; ++pi) {
        const int b  = nw * 4 + pi;   // 0..15
        const int bp = 31 - b;        // mirror

        unsigned fB0[8], fB1[8], fP0[8], fP1[8];
        G1_PAIR(0, fB0, fP0);
        G1_PAIR(1, fB1, fP1);

        gemm2_acc(b,  fB0, fB1);
        gemm2_acc(bp, fP0, fP1);
    }

    // ---- cross-wave reduction: 4 -> 2 -> combine at store
    if (nw >= 2) {
        float* buf = ob + (nw - 2) * (ZT * OS);
        #pragma unroll
        for (int it = 0; it < 3; ++it)
            #pragma unroll
            for (int r = 0; r < 16; ++r)
                buf[((r & 3) + 8 * (r >> 2) + 4 * hi) * OS + it * 32 + l31] = accO[it][r];
    }
    __syncthreads();
    if (nw < 2) {
        float* buf = ob + nw * (ZT * OS);
        #pragma unroll
        for (int it = 0; it < 3; ++it)
            #pragma unroll
            for (int r = 0; r < 16; ++r)
                accO[it][r] += buf[((r & 3) + 8 * (r >> 2) + 4 * hi) * OS + it * 32 + l31];
    }
    __syncthreads();
    if (nw < 2) {
        float* buf = ob + nw * (ZT * OS);
        #pragma unroll
        for (int it = 0; it < 3; ++it)
            #pragma unroll
            for (int r = 0; r < 16; ++r)
                buf[((r & 3) + 8 * (r >> 2) + 4 * hi) * OS + it * 32 + l31] = accO[it][r];
    }
    __syncthreads();

    for (int idx = tid; idx < ZT * DIM; idx += 256) {
        int zz = idx / DIM, ii = idx - zz * DIM;
        out[(size_t)z0 * DIM + idx] = ob[zz * OS + ii] + ob[ZT * OS + zz * OS + ii];
    }
}

// ---------------- fp32 fallback (round-1 kernel; needs no workspace) ----------------
__device__ __forceinline__ float wave_sum64(float v) {
    v += __int_as_float(__builtin_amdgcn_update_dpp(0, __float_as_int(v), 0x111, 0xf, 0xf, true));
    v += __int_as_float(__builtin_amdgcn_update_dpp(0, __float_as_int(v), 0x112, 0xf, 0xf, true));
    v += __int_as_float(__builtin_amdgcn_update_dpp(0, __float_as_int(v), 0x114, 0xf, 0xf, true));
    v += __int_as_float(__builtin_amdgcn_update_dpp(0, __float_as_int(v), 0x118, 0xf, 0xf, true));
    v += __int_as_float(__builtin_amdgcn_update_dpp(0, __float_as_int(v), 0x142, 0xf, 0xf, true));
    v += __int_as_float(__builtin_amdgcn_update_dpp(0, __float_as_int(v), 0x143, 0xf, 0xf, true));
    return v;
}

__global__ __launch_bounds__(256) void gaunt_s2grid_kernel(
    const float* __restrict__ x1, const float* __restrict__ x2,
    const float* __restrict__ shb, const float* __restrict__ sha,
    const float* __restrict__ qw, float* __restrict__ out)
{
    __shared__ float sha_s[64 * DIM];
    __shared__ float part[4 * DIM];
    const int tid = threadIdx.x;
    const int z = blockIdx.x;
    for (int idx = tid; idx < 64 * DIM; idx += 256)
        sha_s[idx] = (idx < RA * DIM) ? sha[idx] : 0.0f;
    __syncthreads();
    const int lane = tid & 63;
    const int w = __builtin_amdgcn_readfirstlane(tid >> 6);
    const int b0 = w * 8;
    const float* xz1 = x1 + (size_t)z * DIM;
    const float* xz2 = x2 + (size_t)z * DIM;
    const float* sha_row = sha_s + lane * DIM;
    float g1[8], g2[8];
    #pragma unroll
    for (int bb = 0; bb < 8; ++bb) { g1[bb] = 0.0f; g2[bb] = 0.0f; }
    #pragma unroll 4
    for (int i = 0; i < DIM; ++i) {
        const float sv = sha_row[i];
        const float t1 = xz1[i] * sv, t2 = xz2[i] * sv;
        #pragma unroll
        for (int bb = 0; bb < 8; ++bb) {
            const float h = shb[(b0 + bb) * DIM + i];
            g1[bb] = fmaf(h, t1, g1[bb]);
            g2[bb] = fmaf(h, t2, g2[bb]);
        }
    }
    float q[8];
    #pragma unroll
    for (int bb = 0; bb < 8; ++bb) q[bb] = g1[bb] * g2[bb] * qw[b0 + bb];
    #pragma unroll 4
    for (int i = 0; i < DIM; ++i) {
        float t = 0.0f;
        #pragma unroll
        for (int bb = 0; bb < 8; ++bb) t = fmaf(q[bb], shb[(b0 + bb) * DIM + i], t);
        float v = wave_sum64(t * sha_row[i]);
        if (lane == 63) part[w * DIM + i] = v;
    }
    __syncthreads();
    for (int i = tid; i < DIM; i += 256)
        out[(size_t)z * DIM + i] = part[i] + part[DIM + i] + part[2 * DIM + i] + part[3 * DIM + i];
}

extern "C" void kernel_launch(void* const* d_in, const int* in_sizes, int n_in,
                              void* d_out, int out_size, void* d_ws, size_t ws_size,
                              hipStream_t stream) {
    const float* x1  = (const float*)d_in[0];
    const float* x2  = (const float*)d_in[1];
    const float* shb = (const float*)d_in[2];
    const float* sha = (const float*)d_in[3];
    const float* qw  = (const float*)d_in[4];
    float* out = (float*)d_out;

    const int Z = in_sizes[0] / DIM;   // 16384

    if (ws_size >= WS_NEED && (Z % ZT) == 0) {
        char* wsp = (char*)d_ws;
        precompute_fact<<<73, 256, 0, stream>>>(shb, sha, qw, wsp);
        gaunt_fact<<<Z / ZT, 256, 0, stream>>>(x1, x2, wsp, out);
    } else {
        gaunt_s2grid_kernel<<<Z, 256, 0, stream>>>(x1, x2, shb, sha, qw, out);
    }
}

// Round 16
// 39.265 us; speedup vs baseline: 1.4819x; 1.4819x over previous
//
#include <hip/hip_runtime.h>

#define DIM 81
#define RA  63
#define RB  32
#define ZT  32
#define XS  104   // X LDS row stride (f16)
#define OS  100   // out-staging row stride (f32)

// workspace offsets (bytes)
#define OFF_SHAA 0        // [at2][kk6][lane64][j8] f16 : 12288 B  (GEMM1 A: sha[a, i])
#define OFF_SHAT 12288    // [it3][ks4][lane64][j8] f16 : 12288 B  (GEMM2 B: sha transposed-packed)
#define OFF_SHBH 24576    // [b32][kk6][hi2][j8]   f16 :  6144 B  (shb[b, i] frag-broadcast)
#define OFF_SHBQ 30720    // [b32][it3][l32]       f32 : 12288 B  (shb[b,i]*qw[b])
#define WS_NEED  43008

// LDS layout: [0,6144) shbH | [6144,18432) shbq | [18432, +25600) xp/ob union
#define LDS_TBL   18432
#define LDS_BYTES (18432 + 25600)

typedef _Float16 half8 __attribute__((ext_vector_type(8)));
typedef _Float16 half4v __attribute__((ext_vector_type(4)));
typedef __fp16  fp16x2 __attribute__((ext_vector_type(2)));
typedef float floatx16 __attribute__((ext_vector_type(16)));

union H8U { unsigned u[4]; half8 h; };
union H2U { fp16x2 h; unsigned u; };

// ---------------- precompute packed sha/shb fragment tables (43 KB total) ----------------
__global__ __launch_bounds__(256) void precompute_fact(
    const float* __restrict__ shb, const float* __restrict__ sha,
    const float* __restrict__ qw, char* __restrict__ wsp)
{
    _Float16* shaAP = (_Float16*)(wsp + OFF_SHAA);
    _Float16* shaTP = (_Float16*)(wsp + OFF_SHAT);
    _Float16* shbHP = (_Float16*)(wsp + OFF_SHBH);
    float*    shbqP = (float*)(wsp + OFF_SHBQ);

    int idx = blockIdx.x * 256 + threadIdx.x;
    if (idx < 6144) {                       // shaAP: A-frag rows a, k = i
        int j = idx & 7, lane = (idx >> 3) & 63, g = idx >> 9;   // g = at*6+kk
        int at = g / 6, kk = g - at * 6;
        int a = at * 32 + (lane & 31);
        int i = kk * 16 + (lane >> 5) * 8 + j;
        float v = (a < RA && i < DIM) ? sha[a * DIM + i] : 0.f;
        shaAP[idx] = (_Float16)v;
    } else if (idx < 12288) {               // shaTP: B-frag cols i, k = a
        int t = idx - 6144;
        int j = t & 7, lane = (t >> 3) & 63, g = t >> 9;          // g = it*4+ks
        int it = g >> 2, ks = g & 3;
        int a = ks * 16 + (lane >> 5) * 8 + j;
        int i = it * 32 + (lane & 31);
        float v = (a < RA && i < DIM) ? sha[a * DIM + i] : 0.f;
        shaTP[t] = (_Float16)v;
    } else if (idx < 15360) {               // shbHP: per-(b,kk,hi) broadcast half8
        int t = idx - 12288;
        int j = t & 7, hi = (t >> 3) & 1, g = t >> 4;             // g = b*6+kk
        int b = g / 6, kk = g - b * 6;
        int i = kk * 16 + hi * 8 + j;
        float v = (i < DIM) ? shb[b * DIM + i] : 0.f;
        shbHP[t] = (_Float16)v;
    } else if (idx < 18432) {               // shbqP: f32 scale per (b, i)
        int t = idx - 15360;
        int l = t & 31, g = t >> 5;                               // g = b*3+it
        int b = g / 3, it = g - b * 3;
        int i = it * 32 + l;
        float v = (i < DIM) ? shb[b * DIM + i] * qw[b] : 0.f;
        shbqP[t] = v;
    }
}

// ---------------- main kernel: R13 + packed-f32 glue + setprio around MFMA ----------------
__global__ __launch_bounds__(256, 1) void gaunt_fact(
    const float* __restrict__ x1, const float* __restrict__ x2,
    const char* __restrict__ wsp, float* __restrict__ out)
{
    const _Float16* shaAP = (const _Float16*)(wsp + OFF_SHAA);
    const _Float16* shaTP = (const _Float16*)(wsp + OFF_SHAT);

    __shared__ __align__(16) char lds[LDS_BYTES];
    const _Float16* shbH_l = (const _Float16*)lds;          // 6144 B
    const float*    shbq_l = (const float*)(lds + 6144);    // 12288 B
    _Float16* xp = (_Float16*)(lds + LDS_TBL);              // [2][ZT][XS]
    float*    ob = (float*)(lds + LDS_TBL);                 // [2][ZT][OS] (reused after xfr reads)

    const int tid = threadIdx.x;
    const int z0  = blockIdx.x * ZT;

    // stage hot tables global->LDS (shbH + shbq contiguous in wsp: 18432 B)
    for (int i = tid; i < LDS_TBL / 16; i += 256)
        ((uint4*)lds)[i] = ((const uint4*)(wsp + OFF_SHBH))[i];

    // stage X1,X2 -> f16 LDS, float4-vectorized (cols 81..95 zero; 81 = 20*4+1)
    {
        const int nv = ZT * 24;
        #pragma unroll
        for (int in = 0; in < 2; ++in) {
            const float* src = in ? x2 : x1;
            _Float16* dst = xp + in * (ZT * XS);
            for (int idx = tid; idx < nv; idx += 256) {
                int r = idx / 24, c4 = idx - r * 24;
                float4 v = make_float4(0.f, 0.f, 0.f, 0.f);
                if (c4 < 20)       v = *(const float4*)(src + (size_t)(z0 + r) * DIM + c4 * 4);
                else if (c4 == 20) v.x = src[(size_t)(z0 + r) * DIM + 80];
                half4v h;
                h[0] = (_Float16)v.x; h[1] = (_Float16)v.y;
                h[2] = (_Float16)v.z; h[3] = (_Float16)v.w;
                *(half4v*)(dst + r * XS + c4 * 4) = h;
            }
        }
    }
    __syncthreads();

    const int l = tid & 63, l31 = l & 31, hi = l >> 5;
    const int nw = tid >> 6;   // wave 0..3, owns b = nw*8 .. +8

    // X B-frags resident in VGPR (48 regs)
    half8 xfr[2][6];
    #pragma unroll
    for (int in = 0; in < 2; ++in)
        #pragma unroll
        for (int kk = 0; kk < 6; ++kk)
            xfr[in][kk] = *(const half8*)(xp + in * (ZT * XS) + l31 * XS + kk * 16 + hi * 8);
    __syncthreads();   // xp reads done; ob (aliased) writable later

    // sha A-frags (unscaled), resident (48 regs)
    half8 aAc[2][6];
    #pragma unroll
    for (int at = 0; at < 2; ++at)
        #pragma unroll
        for (int kk = 0; kk < 6; ++kk)
            aAc[at][kk] = *(const half8*)(shaAP + ((at * 6 + kk) * 64 + l) * 8);

    // GEMM2 B-frags: loop-invariant, hoisted (48 regs)
    half8 bTc[3][2][2];
    #pragma unroll
    for (int it = 0; it < 3; ++it)
        #pragma unroll
        for (int at = 0; at < 2; ++at) {
            bTc[it][at][0] = *(const half8*)(shaTP + ((it * 4 + at * 2) * 64 + l) * 8);
            bTc[it][at][1] = *(const half8*)(shaTP + ((it * 4 + at * 2 + 1) * 64 + l) * 8);
        }

    floatx16 accO[3];
    #pragma unroll
    for (int it = 0; it < 3; ++it)
        #pragma unroll
        for (int r = 0; r < 16; ++r) accO[it][r] = 0.f;

    // GEMM1 + glue: P f16 A-frags for batch row b (sf from LDS)
    auto compute_f = [&](int b, unsigned fO[2][8]) {
        #pragma unroll
        for (int at = 0; at < 2; ++at) {
            floatx16 g0, g1;
            #pragma unroll
            for (int r = 0; r < 16; ++r) { g0[r] = 0.f; g1[r] = 0.f; }
            __builtin_amdgcn_s_setprio(1);
            #pragma unroll
            for (int kk = 0; kk < 6; ++kk) {
                const half8 sf = *(const half8*)(shbH_l + ((b * 6 + kk) * 2 + hi) * 8);
                const half8 aS = aAc[at][kk] * sf;
                g0 = __builtin_amdgcn_mfma_f32_32x32x16_f16(aS, xfr[0][kk], g0, 0, 0, 0);
                g1 = __builtin_amdgcn_mfma_f32_32x32x16_f16(aS, xfr[1][kk], g1, 0, 0, 0);
            }
            __builtin_amdgcn_s_setprio(0);
            // packed product (v_pk_mul_f32) then cvt — one VALU hop from chain end to cvt
            floatx16 p = g0 * g1;
            unsigned q[8];
            #pragma unroll
            for (int j = 0; j < 8; ++j) {
                H2U t;
                t.h = __builtin_amdgcn_cvt_pkrtz(p[2 * j], p[2 * j + 1]);
                q[j] = t.u;
            }
            asm volatile("v_permlane32_swap_b32 %0, %1" : "+v"(q[0]), "+v"(q[2]));
            asm volatile("v_permlane32_swap_b32 %0, %1" : "+v"(q[1]), "+v"(q[3]));
            asm volatile("v_permlane32_swap_b32 %0, %1" : "+v"(q[4]), "+v"(q[6]));
            asm volatile("v_permlane32_swap_b32 %0, %1" : "+v"(q[5]), "+v"(q[7]));
            #pragma unroll
            for (int w = 0; w < 8; ++w) fO[at][w] = q[w];
        }
    };

    // GEMM2 + scaled accumulate for batch row b (s from LDS)
    auto gemm2_acc = [&](int b, const unsigned fI[2][8]) {
        const float s0 = shbq_l[(b * 3 + 0) * 32 + l31];
        const float s1 = shbq_l[(b * 3 + 1) * 32 + l31];
        const float s2 = shbq_l[(b * 3 + 2) * 32 + l31];
        #pragma unroll
        for (int it = 0; it < 3; ++it) {
            floatx16 R;
            #pragma unroll
            for (int r = 0; r < 16; ++r) R[r] = 0.f;
            __builtin_amdgcn_s_setprio(1);
            #pragma unroll
            for (int at = 0; at < 2; ++at) {
                H8U a0, a1;
                a0.u[0] = fI[at][0]; a0.u[1] = fI[at][1]; a0.u[2] = fI[at][2]; a0.u[3] = fI[at][3];
                a1.u[0] = fI[at][4]; a1.u[1] = fI[at][5]; a1.u[2] = fI[at][6]; a1.u[3] = fI[at][7];
                R = __builtin_amdgcn_mfma_f32_32x32x16_f16(a0.h, bTc[it][at][0], R, 0, 0, 0);
                R = __builtin_amdgcn_mfma_f32_32x32x16_f16(a1.h, bTc[it][at][1], R, 0, 0, 0);
            }
            __builtin_amdgcn_s_setprio(0);
            const float s = (it == 0) ? s0 : (it == 1) ? s1 : s2;
            accO[it] += R * s;   // packed v_pk_fma_f32
        }
    };

    // rotated pipeline: GEMM1(b+1) and GEMM2(b) share one basic block
    unsigned fc[2][8], fn[2][8];
    compute_f(nw * 8, fc);
    #pragma unroll 1
    for (int bi = 0; bi < 7; ++bi) {
        compute_f(nw * 8 + bi + 1, fn);
        gemm2_acc(nw * 8 + bi, fc);
        #pragma unroll
        for (int at = 0; at < 2; ++at)
            #pragma unroll
            for (int w = 0; w < 8; ++w) fc[at][w] = fn[at][w];
    }
    gemm2_acc(nw * 8 + 7, fc);

    // ---- cross-wave reduction: 4 -> 2 -> combine at store
    if (nw >= 2) {
        float* buf = ob + (nw - 2) * (ZT * OS);
        #pragma unroll
        for (int it = 0; it < 3; ++it)
            #pragma unroll
            for (int r = 0; r < 16; ++r)
                buf[((r & 3) + 8 * (r >> 2) + 4 * hi) * OS + it * 32 + l31] = accO[it][r];
    }
    __syncthreads();
    if (nw < 2) {
        float* buf = ob + nw * (ZT * OS);
        #pragma unroll
        for (int it = 0; it < 3; ++it)
            #pragma unroll
            for (int r = 0; r < 16; ++r)
                accO[it][r] += buf[((r & 3) + 8 * (r >> 2) + 4 * hi) * OS + it * 32 + l31];
    }
    __syncthreads();
    if (nw < 2) {
        float* buf = ob + nw * (ZT * OS);
        #pragma unroll
        for (int it = 0; it < 3; ++it)
            #pragma unroll
            for (int r = 0; r < 16; ++r)
                buf[((r & 3) + 8 * (r >> 2) + 4 * hi) * OS + it * 32 + l31] = accO[it][r];
    }
    __syncthreads();

    for (int idx = tid; idx < ZT * DIM; idx += 256) {
        int zz = idx / DIM, ii = idx - zz * DIM;
        out[(size_t)z0 * DIM + idx] = ob[zz * OS + ii] + ob[ZT * OS + zz * OS + ii];
    }
}

// ---------------- fp32 fallback (round-1 kernel; needs no workspace) ----------------
__device__ __forceinline__ float wave_sum64(float v) {
    v += __int_as_float(__builtin_amdgcn_update_dpp(0, __float_as_int(v), 0x111, 0xf, 0xf, true));
    v += __int_as_float(__builtin_amdgcn_update_dpp(0, __float_as_int(v), 0x112, 0xf, 0xf, true));
    v += __int_as_float(__builtin_amdgcn_update_dpp(0, __float_as_int(v), 0x114, 0xf, 0xf, true));
    v += __int_as_float(__builtin_amdgcn_update_dpp(0, __float_as_int(v), 0x118, 0xf, 0xf, true));
    v += __int_as_float(__builtin_amdgcn_update_dpp(0, __float_as_int(v), 0x142, 0xf, 0xf, true));
    v += __int_as_float(__builtin_amdgcn_update_dpp(0, __float_as_int(v), 0x143, 0xf, 0xf, true));
    return v;
}

__global__ __launch_bounds__(256) void gaunt_s2grid_kernel(
    const float* __restrict__ x1, const float* __restrict__ x2,
    const float* __restrict__ shb, const float* __restrict__ sha,
    const float* __restrict__ qw, float* __restrict__ out)
{
    __shared__ float sha_s[64 * DIM];
    __shared__ float part[4 * DIM];
    const int tid = threadIdx.x;
    const int z = blockIdx.x;
    for (int idx = tid; idx < 64 * DIM; idx += 256)
        sha_s[idx] = (idx < RA * DIM) ? sha[idx] : 0.0f;
    __syncthreads();
    const int lane = tid & 63;
    const int w = __builtin_amdgcn_readfirstlane(tid >> 6);
    const int b0 = w * 8;
    const float* xz1 = x1 + (size_t)z * DIM;
    const float* xz2 = x2 + (size_t)z * DIM;
    const float* sha_row = sha_s + lane * DIM;
    float g1[8], g2[8];
    #pragma unroll
    for (int bb = 0; bb < 8; ++bb) { g1[bb] = 0.0f; g2[bb] = 0.0f; }
    #pragma unroll 4
    for (int i = 0; i < DIM; ++i) {
        const float sv = sha_row[i];
        const float t1 = xz1[i] * sv, t2 = xz2[i] * sv;
        #pragma unroll
        for (int bb = 0; bb < 8; ++bb) {
            const float h = shb[(b0 + bb) * DIM + i];
            g1[bb] = fmaf(h, t1, g1[bb]);
            g2[bb] = fmaf(h, t2, g2[bb]);
        }
    }
    float q[8];
    #pragma unroll
    for (int bb = 0; bb < 8; ++bb) q[bb] = g1[bb] * g2[bb] * qw[b0 + bb];
    #pragma unroll 4
    for (int i = 0; i < DIM; ++i) {
        float t = 0.0f;
        #pragma unroll
        for (int bb = 0; bb < 8; ++bb) t = fmaf(q[bb], shb[(b0 + bb) * DIM + i], t);
        float v = wave_sum64(t * sha_row[i]);
        if (lane == 63) part[w * DIM + i] = v;
    }
    __syncthreads();
    for (int i = tid; i < DIM; i += 256)
        out[(size_t)z * DIM + i] = part[i] + part[DIM + i] + part[2 * DIM + i] + part[3 * DIM + i];
}

extern "C" void kernel_launch(void* const* d_in, const int* in_sizes, int n_in,
                              void* d_out, int out_size, void* d_ws, size_t ws_size,
                              hipStream_t stream) {
    const float* x1  = (const float*)d_in[0];
    const float* x2  = (const float*)d_in[1];
    const float* shb = (const float*)d_in[2];
    const float* sha = (const float*)d_in[3];
    const float* qw  = (const float*)d_in[4];
    float* out = (float*)d_out;

    const int Z = in_sizes[0] / DIM;   // 16384

    if (ws_size >= WS_NEED && (Z % ZT) == 0) {
        char* wsp = (char*)d_ws;
        precompute_fact<<<72, 256, 0, stream>>>(shb, sha, qw, wsp);
        gaunt_fact<<<Z / ZT, 256, 0, stream>>>(x1, x2, wsp, out);
    } else {
        gaunt_s2grid_kernel<<<Z, 256, 0, stream>>>(x1, x2, shb, sha, qw, out);
    }
}